// Round 1
// baseline (72.355 us; speedup 1.0000x reference)
//
#include <hip/hip_runtime.h>

#define NIMG 8
#define NC 19
#define HW (512*1024)
#define BPI 128          // blocks per image
#define TPB 256
#define ITERS 4          // float4 chunks/thread: (HW/4)/(BPI*TPB) = 131072/32768
#define OLD_CL 11

// ---------------- main pass: per-pixel softmax^2 per-class sums + argmax hist ----------------
__global__ __launch_bounds__(TPB) void iw_main(const float* __restrict__ in,
                                               float* __restrict__ sPart,
                                               unsigned* __restrict__ hPart) {
    const int b   = blockIdx.x;        // 0 .. NIMG*BPI-1
    const int n   = b >> 7;            // image (BPI=128)
    const int bl  = b & (BPI - 1);
    const int tid = threadIdx.x;
    const float* img = in + (size_t)n * NC * HW;

    float    acc[NC];
    unsigned hc[NC];
#pragma unroll
    for (int c = 0; c < NC; ++c) { acc[c] = 0.f; hc[c] = 0u; }

    const float L2E = 1.4426950408889634f;

    for (int it = 0; it < ITERS; ++it) {
        const int    chunk = (bl * TPB + tid) + it * (BPI * TPB);
        const size_t p     = (size_t)chunk * 4;

        float x0[NC], x1[NC], x2[NC], x3[NC];
#pragma unroll
        for (int c = 0; c < NC; ++c) {
            const float4 t = *reinterpret_cast<const float4*>(img + (size_t)c * HW + p);
            x0[c] = t.x; x1[c] = t.y; x2[c] = t.z; x3[c] = t.w;
        }

#define PIXEL(X)                                                            \
        {                                                                   \
            float m = X[0]; int mi = 0;                                     \
            _Pragma("unroll")                                               \
            for (int c = 1; c < NC; ++c) {                                  \
                const bool g = X[c] > m;                                    \
                m  = g ? X[c] : m;                                          \
                mi = g ? c    : mi;                                         \
            }                                                               \
            _Pragma("unroll")                                               \
            for (int c = 0; c < NC; ++c) hc[c] += (mi == c) ? 1u : 0u;      \
            const float ml = m * L2E;                                       \
            float e[NC]; float d = 0.f;                                     \
            _Pragma("unroll")                                               \
            for (int c = 0; c < NC; ++c) {                                  \
                e[c] = exp2f(fmaf(X[c], L2E, -ml));                         \
                d += e[c];                                                  \
            }                                                               \
            const float inv  = 1.0f / d;                                    \
            const float inv2 = inv * inv;                                   \
            _Pragma("unroll")                                               \
            for (int c = 0; c < NC; ++c)                                    \
                acc[c] = fmaf(e[c] * e[c], inv2, acc[c]);                   \
        }

        PIXEL(x0); PIXEL(x1); PIXEL(x2); PIXEL(x3);
#undef PIXEL
    }

    // ---- wave (64-lane) butterfly reduce, per class ----
#pragma unroll
    for (int c = 0; c < NC; ++c) {
#pragma unroll
        for (int off = 32; off >= 1; off >>= 1) {
            acc[c] += __shfl_xor(acc[c], off, 64);
            hc[c]  += (unsigned)__shfl_xor((int)hc[c], off, 64);
        }
    }

    // ---- cross-wave combine via LDS (4 waves/block), deterministic ----
    __shared__ float    ls[TPB / 64][NC];
    __shared__ unsigned lh[TPB / 64][NC];
    const int wave = tid >> 6;
    const int lane = tid & 63;
    if (lane == 0) {
#pragma unroll
        for (int c = 0; c < NC; ++c) { ls[wave][c] = acc[c]; lh[wave][c] = hc[c]; }
    }
    __syncthreads();
    if (tid < NC) {
        float s = 0.f; unsigned h = 0u;
#pragma unroll
        for (int w = 0; w < TPB / 64; ++w) { s += ls[w][tid]; h += lh[w][tid]; }
        sPart[(size_t)b * NC + tid] = s;
        hPart[(size_t)b * NC + tid] = h;
    }
}

// ---------------- final reduce: block partials -> hist -> weight -> scalar loss ----------------
__global__ __launch_bounds__(256) void iw_final(const float* __restrict__ sPart,
                                                const unsigned* __restrict__ hPart,
                                                float* __restrict__ out) {
    __shared__ double contrib[NIMG * NC];
    __shared__ double histL[NIMG * NC];
    __shared__ double hsum[NIMG];
    const int t = threadIdx.x;

    double S = 0.0, H = 0.0;
    if (t < NIMG * NC) {
        const int n = t / NC, c = t % NC;
        double s = 0.0; unsigned h = 0u;
        for (int j = 0; j < BPI; ++j) {
            s += (double)sPart[(size_t)(n * BPI + j) * NC + c];
            h += hPart[(size_t)(n * BPI + j) * NC + c];
        }
        H = (h == 0u) ? 1.0 : (double)h;   // hist[hist==0] = 1
        S = s;
        histL[t] = H;
    }
    __syncthreads();
    if (t < NIMG) {
        double hs = 0.0;
        for (int c = 0; c < NC; ++c) hs += histL[t * NC + c];
        hsum[t] = hs;
    }
    __syncthreads();
    if (t < NIMG * NC) {
        const int n = t / NC, c = t % NC;
        const double w = (c < OLD_CL) ? 1.0 : pow(hsum[n] / H, 0.2);
        contrib[t] = w * S;
    } else if (t < 256) {
        // nothing
    }
    __syncthreads();
    if (t == 0) {
        double tot = 0.0;
        for (int i = 0; i < NIMG * NC; ++i) tot += contrib[i];
        out[0] = (float)(-tot / (double)((size_t)NIMG * NC * HW));
    }
}

extern "C" void kernel_launch(void* const* d_in, const int* in_sizes, int n_in,
                              void* d_out, int out_size, void* d_ws, size_t ws_size,
                              hipStream_t stream) {
    const float* in = (const float*)d_in[0];
    float* out = (float*)d_out;

    float*    sPart = (float*)d_ws;
    unsigned* hPart = (unsigned*)((char*)d_ws + (size_t)NIMG * BPI * NC * sizeof(float));

    iw_main<<<dim3(NIMG * BPI), TPB, 0, stream>>>(in, sPart, hPart);
    iw_final<<<1, 256, 0, stream>>>(sPart, hPart, out);
}